// Round 3
// baseline (182.173 us; speedup 1.0000x reference)
//
#include <hip/hip_runtime.h>

#define BATCH 8
#define CHN 128
#define HH 160
#define WW 160
#define HW (HH*WW)
#define RR 2
#define MAXOFF 5
#define NOFF 25
#define TW 32
#define TH 8
#define PW (TW + 2*RR)     /* 36 */
#define PH (TH + 2*RR)     /* 12 */
#define NG 4
#define CPG (CHN/NG)       /* 32 channels per group */
#define RC 4               /* channels per group per round */
#define SCH (NG*RC)        /* 16 staged channels per round */
#define ROUNDS (CPG/RC)    /* 8 */
#define NPT (TW/2*TH)      /* 128 pixel-threads per group */
#define NTHREADS 512
#define CHFL (PH*PW)       /* 432 floats per staged channel */
#define OCH 5              /* epilogue offset chunk */

__device__ __forceinline__ int reflect_idx(int i, int n) {
    if (i < 0) i = -i;
    if (i >= n) i = 2 * (n - 1) - i;
    return i;
}

__global__ __launch_bounds__(NTHREADS, 6) void costvol_kernel(
    const float* __restrict__ c1,
    const float* __restrict__ c2,
    const float* __restrict__ pw,
    float* __restrict__ out)
{
    __shared__ float lds[SCH * CHFL];   // 27648 B

    const int tid = threadIdx.x;
    const int g  = tid >> 7;            // channel group 0..3
    const int pt = tid & (NPT - 1);     // pixel-thread 0..127
    const int xh = pt & (TW/2 - 1);     // float2 column 0..15
    const int y  = pt >> 4;             // row 0..7
    const int x0 = xh * 2;

    int bidx = blockIdx.x;
    const int tx0 = (bidx % (WW / TW)) * TW; bidx /= (WW / TW);
    const int ty0 = (bidx % (HH / TH)) * TH; bidx /= (HH / TH);
    const int b = bidx;

    float2 acc2[NOFF];
#pragma unroll
    for (int i = 0; i < NOFF; ++i) acc2[i] = make_float2(0.f, 0.f);

    const float* c1p = c1 + ((size_t)b * CHN + g * CPG) * HW + (ty0 + y) * WW + tx0 + x0;
    const float* c2b = c2 + (size_t)b * CHN * HW;
    const float2* lds2 = (const float2*)lds;

    for (int r = 0; r < ROUNDS; ++r) {
        __syncthreads();   // protect lds from previous round's readers
        // stage RC channels for each of the NG groups: reflected 12x36 halo tiles
        for (int idx = tid; idx < SCH * CHFL; idx += NTHREADS) {
            int c   = idx / CHFL;          // staged slot 0..15
            int rem = idx - c * CHFL;
            int ty  = rem / PW;
            int tx  = rem - ty * PW;
            int g2  = c >> 2, j = c & 3;
            int gr  = reflect_idx(ty0 - RR + ty, HH);
            int gc  = reflect_idx(tx0 - RR + tx, WW);
            lds[idx] = c2b[(size_t)(g2 * CPG + r * RC + j) * HW + gr * WW + gc];
        }
        __syncthreads();

#pragma unroll
        for (int j = 0; j < RC; ++j) {
            const float2 s = *(const float2*)(c1p + (size_t)(r * RC + j) * HW);
            const float2* t2 = lds2 + (g * RC + j) * (CHFL / 2);
#pragma unroll
            for (int dy = 0; dy < MAXOFF; ++dy) {
                const int rb = (y + dy) * (PW / 2) + xh;
                const float2 w0 = t2[rb + 0];
                const float2 w1 = t2[rb + 1];
                const float2 w2 = t2[rb + 2];
                float2* A = &acc2[dy * MAXOFF];
                A[0].x = fmaf(s.x, w0.x, A[0].x);  A[0].y = fmaf(s.y, w0.y, A[0].y);
                A[1].x = fmaf(s.x, w0.y, A[1].x);  A[1].y = fmaf(s.y, w1.x, A[1].y);
                A[2].x = fmaf(s.x, w1.x, A[2].x);  A[2].y = fmaf(s.y, w1.y, A[2].y);
                A[3].x = fmaf(s.x, w1.y, A[3].x);  A[3].y = fmaf(s.y, w2.x, A[3].y);
                A[4].x = fmaf(s.x, w2.x, A[4].x);  A[4].y = fmaf(s.y, w2.y, A[4].y);
            }
        }
    }

    // cross-group reduction through LDS, then scale + PReLU + store (group 0)
    const float a = pw[0];
    const float inv_c = 1.0f / (float)CHN;
    float2* e2 = (float2*)lds;   // reuse staging buffer: 3*OCH*NPT float2 = 15 KB

#pragma unroll
    for (int o0 = 0; o0 < NOFF; o0 += OCH) {
        __syncthreads();
        if (g > 0) {
#pragma unroll
            for (int k = 0; k < OCH; ++k)
                e2[((g - 1) * OCH + k) * NPT + pt] = acc2[o0 + k];
        }
        __syncthreads();
        if (g == 0) {
#pragma unroll
            for (int k = 0; k < OCH; ++k) {
                const int o = o0 + k;
                float2 v  = acc2[o];
                float2 v1 = e2[(0 * OCH + k) * NPT + pt];
                float2 v2 = e2[(1 * OCH + k) * NPT + pt];
                float2 v3 = e2[(2 * OCH + k) * NPT + pt];
                float vx = (v.x + v1.x + v2.x + v3.x) * inv_c;
                float vy = (v.y + v1.y + v2.y + v3.y) * inv_c;
                vx = (vx >= 0.f) ? vx : a * vx;
                vy = (vy >= 0.f) ? vy : a * vy;
                *(float2*)(out + (size_t)(b * NOFF + o) * HW + (ty0 + y) * WW + tx0 + x0)
                    = make_float2(vx, vy);
            }
        }
    }
}

extern "C" void kernel_launch(void* const* d_in, const int* in_sizes, int n_in,
                              void* d_out, int out_size, void* d_ws, size_t ws_size,
                              hipStream_t stream) {
    const float* c1 = (const float*)d_in[0];
    const float* c2 = (const float*)d_in[1];
    const float* pw = (const float*)d_in[2];
    float* out = (float*)d_out;

    dim3 grid((WW / TW) * (HH / TH) * BATCH);   // 5*20*8 = 800 blocks
    dim3 block(NTHREADS);
    costvol_kernel<<<grid, block, 0, stream>>>(c1, c2, pw, out);
}